// Round 4
// 6176.439 us; speedup vs baseline: 3.8252x; 3.8252x over previous
//
#include <hip/hip_runtime.h>
#include <cstdint>
#include <cstddef>

typedef short bf8v __attribute__((ext_vector_type(8)));   // 8 bf16 (4 VGPRs)
typedef float f4v  __attribute__((ext_vector_type(4)));   // 4 fp32 acc

#define NT 512
#define NB 64
#define NH 1024
#define NG 4096
#define BH (NB * NH)   // 65536

__device__ __forceinline__ unsigned short f2bf(float f) {
    union { float f; unsigned int i; } v; v.f = f;
    unsigned int u = v.i;
    u += 0x7FFFu + ((u >> 16) & 1u);   // RNE
    return (unsigned short)(u >> 16);
}
__device__ __forceinline__ float gclamp(float x) { return fminf(30.0f, fmaxf(-30.0f, x)); }
__device__ __forceinline__ float sigm(float x)  { x = gclamp(x); return 1.0f / (1.0f + __expf(-x)); }
__device__ __forceinline__ float tanhx(float x) { x = gclamp(x); return 2.0f / (1.0f + __expf(-2.0f * x)) - 1.0f; }

__device__ __forceinline__ bf8v cvt8(const float4 f0, const float4 f1) {
    union { bf8v v; unsigned short s[8]; } u;
    u.s[0] = f2bf(f0.x); u.s[1] = f2bf(f0.y); u.s[2] = f2bf(f0.z); u.s[3] = f2bf(f0.w);
    u.s[4] = f2bf(f1.x); u.s[5] = f2bf(f1.y); u.s[6] = f2bf(f1.z); u.s[7] = f2bf(f1.w);
    return u.v;
}

// ---------------------------------------------------------------------------
// generic fp32 -> bf16 conversion: 8 elements per thread (used for X)
// ---------------------------------------------------------------------------
__global__ __launch_bounds__(256)
void wconv_kernel(const float* __restrict__ src, unsigned short* __restrict__ dst)
{
    const size_t i = ((size_t)blockIdx.x * 256 + threadIdx.x) * 8;
    const float4 f0 = *reinterpret_cast<const float4*>(src + i);
    const float4 f1 = *reinterpret_cast<const float4*>(src + i + 4);
    const bf8v v = cvt8(f0, f1);
    *reinterpret_cast<uint4*>(dst + i) = *reinterpret_cast<const uint4*>(&v);
}

// ---------------------------------------------------------------------------
// Weight re-layout: Wperm[b][16][2048] bf16, pre-XOR-swizzled.
//   block-col b owns H-cols b*4..b*4+3; tile row r = g*4+hc -> W row g*1024+b*4+hc
//   cols 0..1023 = Whh row, 1024..2047 = Wih row
//   stored at ushort idx (r*2048+k) ^ ((r&7)<<3)  (byte-XOR ((r&7)<<4))
// so a LINEAR 64KB copy into LDS leaves data where the swizzled ds_read expects.
// ---------------------------------------------------------------------------
__global__ __launch_bounds__(256)
void wperm_kernel(const float* __restrict__ Whh, const float* __restrict__ Wih,
                  unsigned short* __restrict__ Wp)
{
    const int t  = blockIdx.x * 256 + threadIdx.x;  // 0 .. 1048575
    const int k8 = t & 255;                          // 8-elem chunk within row
    const int rf = t >> 8;                           // 0..4095 = b*16 + r
    const int b  = rf >> 4;
    const int r  = rf & 15;
    const int wr = (r >> 2) * 1024 + b * 4 + (r & 3);
    const int k  = k8 * 8;
    const float* src = (k < 1024) ? (Whh + (size_t)wr * 1024 + k)
                                  : (Wih + (size_t)wr * 1024 + (k - 1024));
    const float4 f0 = *reinterpret_cast<const float4*>(src);
    const float4 f1 = *reinterpret_cast<const float4*>(src + 4);
    const bf8v v = cvt8(f0, f1);
    const int idx = (r * 2048 + k) ^ ((r & 7) << 3);
    *reinterpret_cast<uint4*>(Wp + (size_t)b * 32768 + idx) =
        *reinterpret_cast<const uint4*>(&v);
}

// ---------------------------------------------------------------------------
// c_state = c0 (fp32 copy), hb0 = bf16(h0)
// ---------------------------------------------------------------------------
__global__ __launch_bounds__(256)
void init_kernel(const float* __restrict__ h0, const float* __restrict__ c0,
                 float* __restrict__ c_state, unsigned short* __restrict__ hb0)
{
    const int i = (blockIdx.x * 256 + threadIdx.x) * 4;
#pragma unroll
    for (int k = 0; k < 4; ++k) {
        c_state[i + k] = c0[i + k];
        hb0[i + k] = f2bf(h0[i + k]);
    }
}

// ---------------------------------------------------------------------------
// One LSTM timestep. grid 256 x 256 thr (1 block/CU).
// Block b: 16 gate-matrix cols = {g*1024 + b*4 + hc : g=0..3, hc=0..3}, all 64 rows.
// Wave w = row-tile (batch rows w*16..w*16+15), K = 2048 (h then x), 64 MFMA.
// B resident in LDS (staged once, linear gload_lds from pre-swizzled slab);
// A fragments straight from global (h bf16, x bf16 or fp32). No K-loop barriers.
// ---------------------------------------------------------------------------
template<int XBF16>
__global__ __launch_bounds__(256)
void step_kernel(const void* __restrict__ xt_v,
                 const unsigned short* __restrict__ hp,    // bf16 [64][1024]
                 const unsigned short* __restrict__ Wp,    // bf16 [256][32768] pre-swizzled
                 const float* __restrict__ bih,
                 const float* __restrict__ bhh,
                 float* __restrict__ c_state,
                 unsigned short* __restrict__ hn,          // bf16 [64][1024]
                 float* __restrict__ out_h,
                 float* __restrict__ out_c,
                 const int is_last)
{
    __shared__ __align__(16) unsigned short Bs[16 * 2048]; // 64 KB
    __shared__ float gbuf[4][16][17];                      // ~4.3 KB, padded

    const int tid  = threadIdx.x;
    const int wave = tid >> 6;
    const int lane = tid & 63;
    const int cl   = lane & 15;
    const int quad = lane >> 4;
    const int b    = blockIdx.x;

    // ---- stage this block's 64 KB weight slab into LDS (linear) ----
    {
        const unsigned short* gsrc = Wp + (size_t)b * 32768 + wave * 8192 + lane * 8;
#pragma unroll
        for (int i = 0; i < 16; ++i) {
            __builtin_amdgcn_global_load_lds(
                (const __attribute__((address_space(1))) unsigned int*)(gsrc + i * 512),
                (__attribute__((address_space(3))) unsigned int*)(Bs + wave * 8192 + i * 512),
                16, 0, 0);
        }
    }
    asm volatile("s_waitcnt vmcnt(0)" ::: "memory");
    __syncthreads();

    // ---- K loop: no barriers, B from LDS (swizzled), A from global ----
    f4v acc0 = {0.f, 0.f, 0.f, 0.f};
    f4v acc1 = {0.f, 0.f, 0.f, 0.f};
    const int swz  = (cl & 7) << 3;        // ushort-index XOR (byte (cl&7)<<4)
    const int bq   = quad * 8;
    const int arow = wave * 16 + cl;

    const unsigned short* Ah = hp + (size_t)arow * NH + bq;
#pragma unroll 8
    for (int kt = 0; kt < 32; ++kt) {
        const bf8v a  = *reinterpret_cast<const bf8v*>(Ah + kt * 32);
        const bf8v bb = *reinterpret_cast<const bf8v*>(
            Bs + cl * 2048 + ((kt * 32 + bq) ^ swz));
        if (kt & 1) acc1 = __builtin_amdgcn_mfma_f32_16x16x32_bf16(a, bb, acc1, 0, 0, 0);
        else        acc0 = __builtin_amdgcn_mfma_f32_16x16x32_bf16(a, bb, acc0, 0, 0, 0);
    }

    if (XBF16) {
        const unsigned short* Ax = (const unsigned short*)xt_v + (size_t)arow * NH + bq;
#pragma unroll 8
        for (int kt = 0; kt < 32; ++kt) {
            const bf8v a  = *reinterpret_cast<const bf8v*>(Ax + kt * 32);
            const bf8v bb = *reinterpret_cast<const bf8v*>(
                Bs + cl * 2048 + 1024 + ((kt * 32 + bq) ^ swz));
            if (kt & 1) acc1 = __builtin_amdgcn_mfma_f32_16x16x32_bf16(a, bb, acc1, 0, 0, 0);
            else        acc0 = __builtin_amdgcn_mfma_f32_16x16x32_bf16(a, bb, acc0, 0, 0, 0);
        }
    } else {
        const float* Ax = (const float*)xt_v + (size_t)arow * NH + bq;
#pragma unroll 4
        for (int kt = 0; kt < 32; ++kt) {
            const float4 f0 = *reinterpret_cast<const float4*>(Ax + kt * 32);
            const float4 f1 = *reinterpret_cast<const float4*>(Ax + kt * 32 + 4);
            const bf8v a  = cvt8(f0, f1);
            const bf8v bb = *reinterpret_cast<const bf8v*>(
                Bs + cl * 2048 + 1024 + ((kt * 32 + bq) ^ swz));
            if (kt & 1) acc1 = __builtin_amdgcn_mfma_f32_16x16x32_bf16(a, bb, acc1, 0, 0, 0);
            else        acc0 = __builtin_amdgcn_mfma_f32_16x16x32_bf16(a, bb, acc0, 0, 0, 0);
        }
    }

    // ---- epilogue: C/D layout col = lane&15, row = quad*4 + reg ----
    const f4v acc = acc0 + acc1;
#pragma unroll
    for (int r = 0; r < 4; ++r)
        gbuf[wave][quad * 4 + r][cl] = acc[r];
    __syncthreads();

    // pointwise: wave handles its 16 rows x 4 H-cols, 1 cell per lane
    const int ml  = lane >> 2;            // 0..15 (batch row within tile)
    const int hc  = lane & 3;             // H-col within block
    const int m   = wave * 16 + ml;
    const int col = b * 4 + hc;
    const float gi = gbuf[wave][ml][hc]      + bih[col]          + bhh[col];
    const float gf = gbuf[wave][ml][4 + hc]  + bih[NH + col]     + bhh[NH + col];
    const float gg = gbuf[wave][ml][8 + hc]  + bih[2 * NH + col] + bhh[2 * NH + col];
    const float go = gbuf[wave][ml][12 + hc] + bih[3 * NH + col] + bhh[3 * NH + col];
    const float ig = sigm(gi);
    const float fg = sigm(gf);
    const float g2 = tanhx(gg);
    const float og = sigm(go);
    const size_t off = (size_t)m * NH + col;
    const float cn = fg * c_state[off] + ig * g2;
    const float hv = og * tanhx(cn);
    c_state[off] = cn;
    hn[off] = f2bf(hv);
    out_h[off] = hv;
    if (is_last) out_c[off] = cn;
}

extern "C" void kernel_launch(void* const* d_in, const int* in_sizes, int n_in,
                              void* d_out, int out_size, void* d_ws, size_t ws_size,
                              hipStream_t stream)
{
    (void)in_sizes; (void)n_in; (void)out_size;
    const float* X   = (const float*)d_in[0];
    const float* h0  = (const float*)d_in[1];
    const float* c0  = (const float*)d_in[2];
    const float* Wih = (const float*)d_in[3];
    const float* Whh = (const float*)d_in[4];
    const float* bih = (const float*)d_in[5];
    const float* bhh = (const float*)d_in[6];
    float* out = (float*)d_out;

    // ws layout (bytes) — mandatory footprint 17,301,504 B (== prior proven use):
    //   c_state fp32[BH]            @ 0        (262144)
    //   hb0     bf16[BH]            @ 262144   (131072)
    //   hb1     bf16[BH]            @ 393216   (131072)
    //   Wperm   bf16[256][32768]    @ 524288   (16777216)
    //   xb      bf16[NT*BH]         @ 17301504 (67108864)  [optional]
    char* ws = (char*)d_ws;
    float*          c_state = (float*)(ws);
    unsigned short* hb0     = (unsigned short*)(ws + 262144);
    unsigned short* hb1     = (unsigned short*)(ws + 393216);
    unsigned short* Wperm   = (unsigned short*)(ws + 524288);
    unsigned short* xb      = (unsigned short*)(ws + 17301504);
    const int use_xb = (ws_size >= (size_t)17301504 + (size_t)67108864);

    wperm_kernel<<<4096, 256, 0, stream>>>(Whh, Wih, Wperm);
    init_kernel<<<64, 256, 0, stream>>>(h0, c0, c_state, hb0);
    if (use_xb)
        wconv_kernel<<<16384, 256, 0, stream>>>(X, xb);   // all T at once

    for (int t = 0; t < NT; ++t) {
        const unsigned short* hp = (t & 1) ? hb1 : hb0;
        unsigned short*       hq = (t & 1) ? hb0 : hb1;
        float* out_h = out + (size_t)t * BH;
        float* out_c = out + (size_t)NT * BH;
        if (use_xb)
            step_kernel<1><<<256, 256, 0, stream>>>(
                xb + (size_t)t * BH, hp, Wperm, bih, bhh, c_state, hq,
                out_h, out_c, (t == NT - 1) ? 1 : 0);
        else
            step_kernel<0><<<256, 256, 0, stream>>>(
                X + (size_t)t * BH, hp, Wperm, bih, bhh, c_state, hq,
                out_h, out_c, (t == NT - 1) ? 1 : 0);
    }
}